// Round 15
// baseline (108.707 us; speedup 1.0000x reference)
//
#include <hip/hip_runtime.h>
#include <hip/hip_bf16.h>
#include <math.h>

// ---------------- problem constants ----------------
#define PATCH 14
#define HID   16
#define NCLS  20
#define GX    200
#define GY    200
#define GZ    16
#define NB    2
#define NCAM  6
#define PH    37
#define PW    37
#define NP    (PH*PW)
#define NT    (NB*NCAM*NP)         // 16428 tokens
#define TD    768
#define IMH   518
#define IMW   518
#define PL    ((size_t)GX*GY*GZ)   // 640000 voxels per batch
#define EPSF  1e-5f

// padded conv layout: [b][px 0..201][py 0..201][pz 0..17] rows of 16 ch
#define PX 202
#define PY 202
#define PZ 18

// ---------------- workspace layout (float units) ----------------
#define OFF_VOL   ((size_t)0)            // volf [b][sp][16] fp32 (aliased as staged3 bf16)
#define OFF_CNT   ((size_t)20480000)
#define OFF_ST1   ((size_t)21760000)
#define OFF_ST2   ((size_t)21762048)
#define ZERO_F    ((size_t)21764096)     // zeroing covers OFF_CNT..ZERO_F (done in front kernel)
#define OFF_MATS  ((size_t)21764096)     // 144
#define OFF_WGM   ((size_t)21764240)     // 24*64*8 bf16 = 6,144 f
#define OFF_WA2   ((size_t)21770384)     // 64*8 bf16 = 256 f
#define OFF_C12   ((size_t)21770640)     // 32
#define OFF_WB1A  ((size_t)21770672)     // 3,584
#define OFF_WB1M  ((size_t)21774256)     // 256
#define OFF_WB2   ((size_t)21774512)     // 3,584
#define OFF_S3    ((size_t)21778096)     // 3*16*16 fp32 tap-sums = 768
#define OFF_F1    ((size_t)21778864)     // 2500 bytes = 625 f
#define OFF_F2    ((size_t)21779489)     // 2500 bytes
#define OFF_V2C   ((size_t)21780116)     // 48 bf16 = 24 f
#define WS_FLOATS ((size_t)21780160)

#define ZERO_N4   ((int)((ZERO_F - OFF_CNT) / 4))   // 321,024 float4s

// ---------------- d_out staging (bf16 units; dead before conv3 writes) ----------
#define DO_ST2  ((size_t)0)                       // padded conv1 out, 23,503,104
#define DO_DM   ((size_t)23503104)                // dmean fp32[NT]

typedef __attribute__((ext_vector_type(8))) short short8;
typedef __attribute__((ext_vector_type(4))) float floatx4;

// fast exact-accuracy gelu: A&S 7.1.26 erf, |err| < 1.5e-7, branchless
__device__ __forceinline__ float gelu_exact(float x) {
    float ax = fabsf(x);
    float t  = ax * 0.70710678118654752f;
    float k  = 1.0f / fmaf(t, 0.3275911f, 1.0f);
    float p  = fmaf(k, 1.061405429f, -1.453152027f);
    p = fmaf(p, k, 1.421413741f);
    p = fmaf(p, k, -0.284496736f);
    p = fmaf(p, k, 0.254829592f);
    p = p * k;
    float e = __expf(-t * t);
    float erfabs = fmaf(-p, e, 1.0f);
    return fmaf(0.5f * ax, erfabs, 0.5f * x);
}
__device__ __forceinline__ unsigned short f2bf(float f) {
    __hip_bfloat16 h = __float2bfloat16(f);
    return __builtin_bit_cast(unsigned short, h);
}
__device__ __forceinline__ float bf2f(short u) {
    unsigned int b = ((unsigned int)(unsigned short)u) << 16;
    return __builtin_bit_cast(float, b);
}
__device__ __forceinline__ short8 zero8() {
    short8 z = {0,0,0,0,0,0,0,0};
    return z;
}

// shared geometry: token -> voxel (must match EXACTLY between zero-pass and tokgemm)
__device__ __forceinline__ bool tok_voxel(int tk, float dmr, const float* __restrict__ mats,
                                          int& b, size_t& sp)
{
    int bc = tk / NP;
    int p  = tk - bc * NP;
    b = bc / NCAM;
    int gy = p / PW, gx = p - gy * PW;
    const float* M = mats + bc * 12;
    float dm = fmaxf(dmr, 0.f);
    float u = (gx + 0.5f) * (float)PATCH;
    float v = (gy + 0.5f) * (float)PATCH;
    float lx = (M[0] * u + M[1] * v + M[2]) * dm + M[9];
    float ly = (M[3] * u + M[4] * v + M[5]) * dm + M[10];
    float lz = (M[6] * u + M[7] * v + M[8]) * dm + M[11];
    int cx = (int)floorf((lx + 40.0f) / 0.4f);
    int cy = (int)floorf((ly + 40.0f) / 0.4f);
    int cz = (int)floorf((lz + 1.0f) / 0.4f);
    bool valid = (dmr > 0.001f) &&
                 (unsigned)cx < (unsigned)GX &&
                 (unsigned)cy < (unsigned)GY &&
                 (unsigned)cz < (unsigned)GZ;
    sp = ((size_t)cx * GY + cy) * GZ + cz;
    return valid;
}

// ---------------- 3x3 / 4x4 inverse in double ----------------
__device__ void inv3d(const double* m, double* o) {
    double a=m[0],b=m[1],c=m[2],d=m[3],e=m[4],f=m[5],g=m[6],h=m[7],i=m[8];
    double A=e*i-f*h, B=-(d*i-f*g), C=d*h-e*g;
    double det=a*A+b*B+c*C, id=1.0/det;
    o[0]=A*id;            o[1]=-(b*i-c*h)*id;   o[2]=(b*f-c*e)*id;
    o[3]=B*id;            o[4]=(a*i-c*g)*id;    o[5]=-(a*f-c*d)*id;
    o[6]=C*id;            o[7]=-(a*h-b*g)*id;   o[8]=(a*e-b*d)*id;
}

__device__ void inv4d(const double* m, double* o) {
    double i0  =  m[5]*m[10]*m[15]-m[5]*m[11]*m[14]-m[9]*m[6]*m[15]+m[9]*m[7]*m[14]+m[13]*m[6]*m[11]-m[13]*m[7]*m[10];
    double i4  = -m[4]*m[10]*m[15]+m[4]*m[11]*m[14]+m[8]*m[6]*m[15]-m[8]*m[7]*m[14]-m[12]*m[6]*m[11]+m[12]*m[7]*m[10];
    double i8  =  m[4]*m[9]*m[15]-m[4]*m[11]*m[13]-m[8]*m[5]*m[15]+m[8]*m[7]*m[13]+m[12]*m[5]*m[11]-m[12]*m[7]*m[9];
    double i12 = -m[4]*m[9]*m[14]+m[4]*m[10]*m[13]+m[8]*m[5]*m[14]-m[8]*m[6]*m[13]-m[12]*m[5]*m[10]+m[12]*m[6]*m[9];
    double i1  = -m[1]*m[10]*m[15]+m[1]*m[11]*m[14]+m[9]*m[2]*m[15]-m[9]*m[3]*m[14]-m[13]*m[2]*m[11]+m[13]*m[3]*m[10];
    double i5  =  m[0]*m[10]*m[15]-m[0]*m[11]*m[14]-m[8]*m[2]*m[15]+m[8]*m[3]*m[14]+m[12]*m[2]*m[11]-m[12]*m[3]*m[10];
    double i9  = -m[0]*m[9]*m[15]+m[0]*m[11]*m[13]+m[8]*m[1]*m[15]-m[8]*m[3]*m[13]-m[12]*m[1]*m[11]+m[12]*m[3]*m[9];
    double i13 =  m[0]*m[9]*m[14]-m[0]*m[10]*m[13]-m[8]*m[1]*m[14]+m[8]*m[2]*m[13]+m[12]*m[1]*m[10]-m[12]*m[2]*m[9];
    double i2  =  m[1]*m[6]*m[15]-m[1]*m[7]*m[14]-m[5]*m[2]*m[15]+m[5]*m[3]*m[14]+m[13]*m[2]*m[7]-m[13]*m[3]*m[6];
    double i6  = -m[0]*m[6]*m[15]+m[0]*m[7]*m[14]+m[4]*m[2]*m[15]-m[4]*m[3]*m[14]-m[12]*m[2]*m[7]+m[12]*m[3]*m[6];
    double i10 =  m[0]*m[5]*m[15]-m[0]*m[7]*m[13]-m[4]*m[1]*m[15]+m[4]*m[3]*m[13]+m[12]*m[1]*m[7]-m[12]*m[3]*m[5];
    double i14 = -m[0]*m[5]*m[14]+m[0]*m[6]*m[13]+m[4]*m[1]*m[14]-m[4]*m[2]*m[13]-m[12]*m[1]*m[6]+m[12]*m[2]*m[5];
    double i3  = -m[1]*m[6]*m[11]+m[1]*m[7]*m[10]+m[5]*m[2]*m[11]-m[5]*m[3]*m[10]-m[9]*m[2]*m[7]+m[9]*m[3]*m[6];
    double i7  =  m[0]*m[6]*m[11]-m[0]*m[7]*m[10]-m[4]*m[2]*m[11]+m[4]*m[3]*m[10]+m[8]*m[2]*m[7]-m[8]*m[3]*m[6];
    double i11 = -m[0]*m[5]*m[11]+m[0]*m[7]*m[9]+m[4]*m[1]*m[11]-m[4]*m[3]*m[9]-m[8]*m[1]*m[7]+m[8]*m[3]*m[5];
    double i15 =  m[0]*m[5]*m[10]-m[0]*m[6]*m[9]-m[4]*m[1]*m[10]+m[4]*m[2]*m[9]+m[8]*m[1]*m[6]-m[8]*m[2]*m[5];
    double det = m[0]*i0+m[1]*i4+m[2]*i8+m[3]*i12;
    double id = 1.0/det;
    o[0]=i0*id; o[1]=i1*id; o[2]=i2*id; o[3]=i3*id;
    o[4]=i4*id; o[5]=i5*id; o[6]=i6*id; o[7]=i7*id;
    o[8]=i8*id; o[9]=i9*id; o[10]=i10*id; o[11]=i11*id;
    o[12]=i12*id; o[13]=i13*id; o[14]=i14*id; o[15]=i15*id;
}

// compute cam bc's fused matrix (rows of 12 floats)
__device__ void cam_mat(int t, const float* __restrict__ intr, const float* __restrict__ c2w,
                        const float* __restrict__ l2w, float* __restrict__ out12)
{
    int b = t / NCAM;
    double K[9], Ki[9], L[16], Li[16], C[16], M[16], A[9];
    #pragma unroll
    for (int i = 0; i < 9; ++i) K[i] = (double)intr[t * 9 + i];
    inv3d(K, Ki);
    #pragma unroll
    for (int i = 0; i < 16; ++i) L[i] = (double)l2w[b * 16 + i];
    inv4d(L, Li);
    #pragma unroll
    for (int i = 0; i < 16; ++i) C[i] = (double)c2w[t * 16 + i];
    #pragma unroll
    for (int r = 0; r < 4; ++r)
        #pragma unroll
        for (int c = 0; c < 4; ++c) {
            double s = 0.0;
            #pragma unroll
            for (int k = 0; k < 4; ++k) s += Li[r * 4 + k] * C[k * 4 + c];
            M[r * 4 + c] = s;
        }
    #pragma unroll
    for (int r = 0; r < 3; ++r)
        #pragma unroll
        for (int c = 0; c < 3; ++c) {
            double s = 0.0;
            #pragma unroll
            for (int k = 0; k < 3; ++k) s += M[r * 4 + k] * Ki[k * 3 + c];
            A[r * 3 + c] = s;
        }
    #pragma unroll
    for (int i = 0; i < 9; ++i) out12[i] = (float)A[i];
    out12[9]  = (float)M[3];
    out12[10] = (float)M[7];
    out12[11] = (float)M[11];
}

// ---- prep0: one block -- cam matrices (double), c12, S3 ----
__global__ __launch_bounds__(256) void occ_prep0_kernel(
    const float* __restrict__ intr, const float* __restrict__ c2w,
    const float* __restrict__ l2w, const float* __restrict__ w1,
    const float* __restrict__ ln_g, const float* __restrict__ ln_b,
    const float* __restrict__ b1, const float* __restrict__ cw2,
    float* __restrict__ mats, float* __restrict__ c12, float* __restrict__ S3)
{
    __shared__ float sc1[256], sc2[256];
    int tid = threadIdx.x;

    if (tid < NB * NCAM) cam_mat(tid, intr, c2w, l2w, &mats[tid * 12]);

    // c12 reduction (all 256 threads)
    {
        int j = tid & 15, ck = tid >> 4;
        float c1 = 0.f, c2p = 0.f;
        #pragma unroll 4
        for (int dd = 0; dd < TD / 16; ++dd) {
            int d = ck * (TD / 16) + dd;
            c1  += bf2f((short)f2bf(ln_g[d] * w1[d * 16 + j]));
            c2p += ln_b[d] * w1[d * 16 + j];
        }
        sc1[tid] = c1; sc2[tid] = c2p;
    }
    __syncthreads();
    if (tid < 16) {
        float a1 = 0.f, a2 = 0.f;
        #pragma unroll
        for (int k = 0; k < 16; ++k) { a1 += sc1[k * 16 + tid]; a2 += sc2[k * 16 + tid]; }
        c12[tid] = a1;
        c12[16 + tid] = a2 + b1[tid];
    }

    // S3 tap-sums (768 entries, 3 per thread)
    for (int i = tid; i < 3 * 16 * 16; i += 256) {
        int cse = i >> 8; int r = i & 255; int o = r >> 4; int ci = r & 15;
        int kwlo = (cse == 0) ? 1 : 0;
        int kwhi = (cse == 2) ? 1 : 2;
        float s = 0.f;
        for (int kd = 0; kd < 3; ++kd)
            for (int kh = 0; kh < 3; ++kh)
                for (int kw = kwlo; kw <= kwhi; ++kw)
                    s += bf2f((short)f2bf(cw2[(o * 16 + ci) * 27 + (kd * 9 + kh * 3 + kw)]));
        S3[i] = s;
    }
}

// ---- front kernel: depth means + vol scatter-zero + cnt/stats zero + weight packs ----
// (barrier-free; mats read from global, precomputed by prep0)
__global__ __launch_bounds__(256) void occ_front_kernel(
    const float* __restrict__ depth, const float* __restrict__ mats,
    const float* __restrict__ w1, const float* __restrict__ ln_g,
    const float* __restrict__ w2, const float* __restrict__ cw1,
    const float* __restrict__ cw2,
    __hip_bfloat16* __restrict__ wGm, __hip_bfloat16* __restrict__ wA2,
    __hip_bfloat16* __restrict__ wB1a, __hip_bfloat16* __restrict__ wB1m,
    __hip_bfloat16* __restrict__ wB2,
    float* __restrict__ dmean, float* __restrict__ vol, float4* __restrict__ zbase)
{
    int tid = threadIdx.x;
    int bid = blockIdx.x;
    int gt = bid * 256 + tid;

    if (gt < ZERO_N4) {
        float4 z = {0.f, 0.f, 0.f, 0.f};
        zbase[gt] = z;
    }

    int l = tid & 63;
    int g = bid * 4 + (tid >> 6);
    int bc = g / NP;
    int p  = g - bc * NP;
    int gy = p / PW, gx = p - gy * PW;
    const float* dbase = depth + (size_t)bc * (IMH * IMW);
    int rbase = gy * PATCH, cb = gx * PATCH;
    float dsum = 0.f;
    #pragma unroll
    for (int i = 0; i < 3; ++i) {
        int idx = l + 64 * i;
        int py = idx / 14;
        int px = idx - py * 14;
        dsum += dbase[(size_t)(rbase + py) * IMW + (cb + px)];
    }
    if (l < 4)
        dsum += dbase[(size_t)(rbase + 13) * IMW + (cb + 10 + l)];

    if (gt < 24 * 64 * 8) {
        int i = gt;
        int st = i >> 9; int ln = (i >> 3) & 63; int e = i & 7;
        int kg = ln >> 4, j = ln & 15;
        int d = st * 32 + kg * 8 + e;
        wGm[i] = __float2bfloat16(ln_g[d] * w1[d * 16 + j]);
    }
    if (gt < 64 * 8) {
        int i = gt;
        int ln = i >> 3; int e = i & 7;
        int kg = ln >> 4, ch = ln & 15;
        int k = kg * 8 + e;
        wA2[i] = __float2bfloat16((k < 16) ? w2[k * 16 + ch] : 0.f);
    }
    if (gt < 14 * 64 * 8) {
        int i = gt;
        int t2 = i >> 9; int r = i & 511; int ln = r >> 3; int e = r & 7;
        int kg = ln >> 4;
        int tt = 2 * t2 + (kg >> 1);
        int ci = ((kg & 1) << 3) + e;
        int o = ln & 15;
        float val = (tt < 27) ? cw1[(o * 17 + ci) * 27 + tt] : 0.f;
        wB1a[i] = __float2bfloat16(val);
    }
    if (gt < 64 * 8) {
        int i = gt;
        int ln = i >> 3; int e = i & 7;
        int k = ((ln >> 4) << 3) + e;
        int o = ln & 15;
        float val = (k < 27) ? cw1[(o * 17 + 16) * 27 + k] : 0.f;
        wB1m[i] = __float2bfloat16(val);
    }
    if (gt < 14 * 64 * 8) {
        int i = gt;
        int t2 = i >> 9; int r = i & 511; int ln = r >> 3; int e = r & 7;
        int kg = ln >> 4;
        int tt = 2 * t2 + (kg >> 1);
        int ci = ((kg & 1) << 3) + e;
        int o = ln & 15;
        float val = (tt < 27) ? cw2[(o * 16 + ci) * 27 + tt] : 0.f;
        wB2[i] = __float2bfloat16(val);
    }

    // depth reduce (intra-wave, no barrier) + dmean + scatter-zero vol rows
    #pragma unroll
    for (int m = 1; m <= 32; m <<= 1) dsum += __shfl_xor(dsum, m);
    float dmr = dsum * (1.0f / 196.0f);
    if (l == 0) dmean[g] = dmr;
    if (l < 4) {
        int b; size_t sp;
        if (tok_voxel(g, dmr, mats, b, sp)) {
            float4 z = {0.f, 0.f, 0.f, 0.f};
            *(float4*)(vol + ((size_t)b * PL + sp) * 16 + l * 4) = z;
        }
    }
}

// ------- token GEMM: K-split x2 (2 waves per 16-token group); LN in epilogue -------
__global__ __launch_bounds__(512) void occ_tokgemm_kernel(
    const float* __restrict__ tokens, const float* __restrict__ dmean,
    const __hip_bfloat16* __restrict__ wGm, const __hip_bfloat16* __restrict__ wA2,
    const float* __restrict__ c12, const float* __restrict__ b2,
    const float* __restrict__ mats, float* __restrict__ vol, float* __restrict__ cnt)
{
    int tid = threadIdx.x;
    int w = tid >> 6, lane = tid & 63;
    int grp = w & 3, half = w >> 2;
    int tile = (blockIdx.x * 4 + grp) * 16;
    int j16 = lane & 15, kg = lane >> 4;

    __shared__ float sPart[4][64][6];          // partials from half=1 waves
    __shared__ __hip_bfloat16 sH[4][16][16];

    int tka  = tile + j16;
    int tkac = min(tka, NT - 1);

    const float* tokp = tokens + (size_t)tkac * TD + (kg << 3);
    const short8* wg8 = (const short8*)wGm;

    floatx4 acc = {0.f, 0.f, 0.f, 0.f};
    float s = 0.f, sq = 0.f;
    #pragma unroll
    for (int st2 = 0; st2 < 12; ++st2) {
        int st = half * 12 + st2;
        float4 xa = *(const float4*)(tokp + st * 32);
        float4 xb = *(const float4*)(tokp + st * 32 + 4);
        s += xa.x + xa.y + xa.z + xa.w + xb.x + xb.y + xb.z + xb.w;
        sq = fmaf(xa.x, xa.x, sq); sq = fmaf(xa.y, xa.y, sq);
        sq = fmaf(xa.z, xa.z, sq); sq = fmaf(xa.w, xa.w, sq);
        sq = fmaf(xb.x, xb.x, sq); sq = fmaf(xb.y, xb.y, sq);
        sq = fmaf(xb.z, xb.z, sq); sq = fmaf(xb.w, xb.w, sq);
        short8 a;
        a[0] = (short)f2bf(xa.x); a[1] = (short)f2bf(xa.y);
        a[2] = (short)f2bf(xa.z); a[3] = (short)f2bf(xa.w);
        a[4] = (short)f2bf(xb.x); a[5] = (short)f2bf(xb.y);
        a[6] = (short)f2bf(xb.z); a[7] = (short)f2bf(xb.w);
        acc = __builtin_amdgcn_mfma_f32_16x16x32_bf16(a, wg8[st * 64 + lane], acc, 0, 0, 0);
    }

    if (half == 1) {
        sPart[grp][lane][0] = acc[0]; sPart[grp][lane][1] = acc[1];
        sPart[grp][lane][2] = acc[2]; sPart[grp][lane][3] = acc[3];
        sPart[grp][lane][4] = s;      sPart[grp][lane][5] = sq;
    }
    __syncthreads();

    if (half == 0) {
        acc[0] += sPart[grp][lane][0]; acc[1] += sPart[grp][lane][1];
        acc[2] += sPart[grp][lane][2]; acc[3] += sPart[grp][lane][3];
        s += sPart[grp][lane][4];      sq += sPart[grp][lane][5];

        s  += __shfl_xor(s, 16);  s  += __shfl_xor(s, 32);
        sq += __shfl_xor(sq, 16); sq += __shfl_xor(sq, 32);
        float mu = s * (1.0f / (float)TD);
        float rs = rsqrtf(sq * (1.0f / (float)TD) - mu * mu + EPSF);

        float c1  = c12[j16];
        float c2p = c12[16 + j16];
        #pragma unroll
        for (int r = 0; r < 4; ++r) {
            int srcl = kg * 4 + r;
            float mur = __shfl(mu, srcl, 16);
            float rsr = __shfl(rs, srcl, 16);
            float h = rsr * (acc[r] - mur * c1) + c2p;
            sH[grp][srcl][j16] = __float2bfloat16(gelu_exact(h));
        }
    }
    __syncthreads();

    if (half == 0) {
        short8 hb = zero8();
        if (kg < 2) hb = *(const short8*)&sH[grp][j16][kg * 8];
        floatx4 acc2;
        acc2[0] = b2[kg * 4 + 0]; acc2[1] = b2[kg * 4 + 1];
        acc2[2] = b2[kg * 4 + 2]; acc2[3] = b2[kg * 4 + 3];
        short8 a2 = ((const short8*)wA2)[lane];
        acc2 = __builtin_amdgcn_mfma_f32_16x16x32_bf16(a2, hb, acc2, 0, 0, 0);

        int b; size_t sp;
        bool valid = tok_voxel(tkac, dmean[tkac], mats, b, sp) && (tka < NT);
        if (valid) {
            float* base = vol + ((size_t)b * PL + sp) * 16 + kg * 4;
            atomicAdd(base + 0, acc2[0]);
            atomicAdd(base + 1, acc2[1]);
            atomicAdd(base + 2, acc2[2]);
            atomicAdd(base + 3, acc2[3]);
            if (kg == 0) atomicAdd(cnt + (size_t)b * PL + sp, 1.0f);
        }
    }
}

// ------- conv3d 3x3x3 via MFMA, LDS-staged 4x8 tile, sparse tile+write skipping -------
// MODE 0 (conv1): normalize-on-stage; empty -> flag F1, skip MFMA AND stores
// MODE 1 (conv2): bn1-finalize; stage substitutes const for F1 rows; const tile ->
//                 skip stage/MFMA/stores (conv3 uses sV3 via F2)
template <int MODE>
__global__ __launch_bounds__(256, 4) void occ_conv_kernel(
    const float* __restrict__ volf, const float* __restrict__ cnt,
    const __hip_bfloat16* __restrict__ inbf,
    const float* __restrict__ statsIn, const float* __restrict__ gIn,
    const float* __restrict__ bbIn, const float* __restrict__ cv1bIn,
    const float* __restrict__ S3, unsigned char* __restrict__ F1,
    unsigned char* __restrict__ F2, unsigned short* __restrict__ v2c,
    const __hip_bfloat16* __restrict__ wBa, const __hip_bfloat16* __restrict__ wBm,
    const float* __restrict__ bias, __hip_bfloat16* __restrict__ out,
    float* __restrict__ statsOut)
{
    int bid = blockIdx.x;
    int xcd = bid & 7, off = bid >> 3;
    int blk = (xcd < 4 ? xcd * 313 : 4 * 313 + (xcd - 4) * 312) + off;
    int b   = blk / 1250;
    int rem = blk % 1250;
    int x0  = (rem / 25) * 4;
    int y0  = (rem % 25) * 8;
    int tid = threadIdx.x;

    __shared__ __hip_bfloat16 sA[1080 * 16];
    __shared__ unsigned short sM[1080];
    __shared__ float sred[8][32];
    __shared__ float sbn[32];
    __shared__ float sG1[16];
    __shared__ unsigned short sGBc[16];   // bf16 of gelu(bn1(bf16(cv1b)))
    __shared__ float sV[3][16];
    __shared__ int sFlag;

    if constexpr (MODE == 1) {
        {
            int c = tid & 31, k = tid >> 5;
            float s = 0.f;
            #pragma unroll
            for (int i = 0; i < 8; ++i) s += statsIn[(size_t)(k * 8 + i) * 32 + c];
            sred[k][c] = s;
        }
        __syncthreads();
        if (tid < 32) {
            float a = 0.f;
            #pragma unroll
            for (int i = 0; i < 8; ++i) a += sred[i][tid];
            sred[0][tid] = a;
        }
        __syncthreads();
        if (tid < 16) {
            const float N = (float)(NB * PL);
            float mean = sred[0][tid] / N;
            float var  = sred[0][16 + tid] / N - mean * mean;
            float scale = gIn[tid] * rsqrtf(var + EPSF);
            sbn[tid] = scale;
            sbn[16 + tid] = bbIn[tid] - mean * scale;
        }
        if (tid == 0) {
            int xt = rem / 25, yt = rem % 25;
            int ok = (xt >= 1 && xt <= 48 && yt >= 1 && yt <= 23) ? 1 : 0;
            if (ok) {
                #pragma unroll
                for (int dx = -1; dx <= 1; ++dx)
                    #pragma unroll
                    for (int dy = -1; dy <= 1; ++dy)
                        if (!F1[b * 1250 + (xt + dx) * 25 + (yt + dy)]) ok = 0;
            }
            sFlag = ok;
        }
        __syncthreads();
        if (tid < 16) {
            float bf16bias = bf2f((short)f2bf(cv1bIn[tid]));
            float gval = gelu_exact(fmaf(bf16bias, sbn[tid], sbn[16 + tid]));
            sG1[tid] = gval;
            sGBc[tid] = f2bf(gval);
        }
        __syncthreads();
    } else {
        if (tid == 0) sFlag = 0;
        __syncthreads();
    }

    bool skip2 = false;
    if constexpr (MODE == 1) skip2 = (sFlag != 0);

    if (!skip2) {
        short8* sa8 = (short8*)sA;
        const short8* gin = (const short8*)inbf;
        for (int ii = tid; ii < 1080; ii += 256) {
            int dx = ii / 180;
            int r2 = ii - dx * 180;
            int dy = r2 / 18, dz = r2 - dy * 18;
            int px = x0 + dx, py = y0 + dy, pz = dz;
            bool interior = ((unsigned)(px - 1) < (unsigned)GX) &&
                            ((unsigned)(py - 1) < (unsigned)GY) &&
                            ((unsigned)(pz - 1) < (unsigned)GZ);
            short8 o0 = zero8(), o1 = zero8();
            if constexpr (MODE == 0) {
                unsigned short m = 0;
                if (interior) {
                    size_t vi = (size_t)b * PL +
                                (((size_t)(px - 1) * GY + (py - 1)) * GZ + (pz - 1));
                    float cn = cnt[vi];
                    if (cn > 0.f) {
                        float inv = 1.0f / cn;
                        const float4* vp = (const float4*)(volf + vi * 16);
                        float4 f0 = vp[0], f1 = vp[1], f2 = vp[2], f3 = vp[3];
                        o0[0] = (short)f2bf(f0.x * inv); o0[1] = (short)f2bf(f0.y * inv);
                        o0[2] = (short)f2bf(f0.z * inv); o0[3] = (short)f2bf(f0.w * inv);
                        o0[4] = (short)f2bf(f1.x * inv); o0[5] = (short)f2bf(f1.y * inv);
                        o0[6] = (short)f2bf(f1.z * inv); o0[7] = (short)f2bf(f1.w * inv);
                        o1[0] = (short)f2bf(f2.x * inv); o1[1] = (short)f2bf(f2.y * inv);
                        o1[2] = (short)f2bf(f2.z * inv); o1[3] = (short)f2bf(f2.w * inv);
                        o1[4] = (short)f2bf(f3.x * inv); o1[5] = (short)f2bf(f3.y * inv);
                        o1[6] = (short)f2bf(f3.z * inv); o1[7] = (short)f2bf(f3.w * inv);
                        m = f2bf(1.0f);
                        sFlag = 1;                       // benign race: any-occupied
                    }
                }
                sM[ii] = m;
            } else {
                if (interior) {
                    int ti = b * 1250 + ((px - 1) >> 2) * 25 + ((py - 1) >> 3);
                    if (F1[ti]) {
                        #pragma unroll
                        for (int e = 0; e < 8; ++e) {
                            o0[e] = (short)sGBc[e];
                            o1[e] = (short)sGBc[8 + e];
                        }
                    } else {
                        size_t grow = ((size_t)((b * PX + px) * PY + py) * PZ) + pz;
                        short8 v0 = gin[grow * 2], v1 = gin[grow * 2 + 1];
                        #pragma unroll
                        for (int e = 0; e < 8; ++e) {
                            o0[e] = (short)f2bf(gelu_exact(fmaf(bf2f(v0[e]), sbn[e],     sbn[16 + e])));
                            o1[e] = (short)f2bf(gelu_exact(fmaf(bf2f(v1[e]), sbn[8 + e], sbn[24 + e])));
                        }
                    }
                }
            }
            sa8[ii * 2] = o0; sa8[ii * 2 + 1] = o1;
        }
    }
    __syncthreads();

    bool empty1 = false;
    if constexpr (MODE == 0) {
        empty1 = (sFlag == 0);
        if (tid == 0) F1[b * 1250 + rem] = empty1 ? 1 : 0;
    } else {
        if (skip2 && tid < 48) {
            int cse = tid >> 4, o = tid & 15;
            float a = bias[o];
            #pragma unroll
            for (int ci = 0; ci < 16; ++ci)
                a = fmaf(sG1[ci], S3[cse * 256 + o * 16 + ci], a);
            sV[cse][o] = a;
            v2c[tid] = f2bf(a);
        }
        if (tid == 0) F2[b * 1250 + rem] = skip2 ? 1 : 0;
        __syncthreads();
    }

    int w = tid >> 6, lane = tid & 63;
    int z = lane & 15, kg = lane >> 4;
    int ci0 = (kg & 1) << 3;
    bool halfsel = kg >= 2;

    float bo = bias[lane & 15];
    floatx4 acc[8];
    #pragma unroll
    for (int j = 0; j < 8; ++j) { acc[j][0]=bo; acc[j][1]=bo; acc[j][2]=bo; acc[j][3]=bo; }

    bool doMfma = (MODE == 0) ? !empty1 : !skip2;
    if (doMfma) {
        const short8* wp = (const short8*)wBa;
        short8 wreg[14];
        #pragma unroll
        for (int t2 = 0; t2 < 14; ++t2) wreg[t2] = wp[t2 * 64 + lane];

        #pragma unroll
        for (int t2 = 0; t2 < 14; ++t2) {
            const int ta = 2 * t2;
            const int tb = (2 * t2 + 1 > 26) ? 26 : 2 * t2 + 1;
            const int kda = ta / 9, kha = (ta / 3) % 3, kwa = ta % 3;
            const int kdb = tb / 9, khb = (tb / 3) % 3, kwb = tb % 3;
            int rowA = (w + kda) * 180 + kha * 18 + (z + kwa);
            int rowB = (w + kdb) * 180 + khb * 18 + (z + kwb);
            int row = halfsel ? rowB : rowA;
            const __hip_bfloat16* ap = sA + row * 16 + ci0;
            #pragma unroll
            for (int j = 0; j < 8; ++j) {
                short8 a = *(const short8*)(ap + j * (18 * 16));
                acc[j] = __builtin_amdgcn_mfma_f32_16x16x32_bf16(a, wreg[t2], acc[j], 0, 0, 0);
            }
        }

        if constexpr (MODE == 0) {
            int base8[8];
            #pragma unroll
            for (int e = 0; e < 8; ++e) {
                int tap = kg * 8 + e;
                int kd = tap / 9;
                int rm = tap - kd * 9;
                int kh = rm / 3;
                int kw = rm - kh * 3;
                int idx = (w + kd) * 180 + kh * 18 + z + kw;
                base8[e] = (tap < 27) ? idx : 0;
            }
            short8 wm = ((const short8*)wBm)[lane];
            #pragma unroll
            for (int j = 0; j < 8; ++j) {
                short8 am;
                #pragma unroll
                for (int e = 0; e < 8; ++e) am[e] = (short)sM[base8[e] + j * 18];
                acc[j] = __builtin_amdgcn_mfma_f32_16x16x32_bf16(am, wm, acc[j], 0, 0, 0);
            }
        }
    } else if (MODE == 1 && skip2) {
        int o = lane & 15;
        #pragma unroll
        for (int r = 0; r < 4; ++r) {
            int zp = kg * 4 + r;
            int cse = (zp == 0) ? 0 : ((zp == 15) ? 2 : 1);
            float v = sV[cse][o];
            #pragma unroll
            for (int j = 0; j < 8; ++j) acc[j][r] = v;
        }
    }

    bool doStore = (MODE == 0) ? !empty1 : !skip2;
    if (doStore) {
        int o = lane & 15;
        int wx = x0 + w;
        #pragma unroll
        for (int j = 0; j < 8; ++j) {
            int wy = y0 + j;
            size_t rowbase;
            if constexpr (MODE == 0)
                rowbase = (size_t)(((b * PX + wx + 1) * PY) + (wy + 1)) * PZ + 1;
            else
                rowbase = (size_t)b * PL + ((size_t)wx * GY + wy) * GZ;
            #pragma unroll
            for (int r = 0; r < 4; ++r)
                out[(rowbase + kg * 4 + r) * 16 + o] = __float2bfloat16(acc[j][r]);
        }
    }

    float s = 0.f, sq = 0.f;
    #pragma unroll
    for (int j = 0; j < 8; ++j)
        #pragma unroll
        for (int r = 0; r < 4; ++r) { float v = acc[j][r]; s += v; sq += v * v; }
    s  += __shfl_xor(s, 16);  s  += __shfl_xor(s, 32);
    sq += __shfl_xor(sq, 16); sq += __shfl_xor(sq, 32);
    __syncthreads();
    if (lane < 16) { sred[w][lane] = s; sred[w][16 + lane] = sq; }
    __syncthreads();
    if (tid < 32) {
        float v2 = sred[0][tid] + sred[1][tid] + sred[2][tid] + sred[3][tid];
        atomicAdd(&statsOut[(size_t)(blockIdx.x & 63) * 32 + tid], v2);
    }
}

// -------- conv3 1x1x1 (16 -> 20): per-block bn2 finalize, const-tile fast path,
//          2 voxels per thread (2500 blocks) --------
__global__ __launch_bounds__(256) void occ_conv3_kernel(const __hip_bfloat16* __restrict__ act,
                                                        const float* __restrict__ statsIn,
                                                        const float* __restrict__ gIn,
                                                        const float* __restrict__ bbIn,
                                                        const unsigned char* __restrict__ F2,
                                                        const unsigned short* __restrict__ v2c,
                                                        const float* __restrict__ w3,
                                                        const float* __restrict__ b3,
                                                        float* __restrict__ out)
{
    __shared__ float w[NCLS * 16];
    __shared__ float bb[NCLS];
    __shared__ float sred[8][32];
    __shared__ float sc[16], sh[16];
    __shared__ float sG2[3][16];
    __shared__ float sV3[3][NCLS];
    int t = threadIdx.x;
    {
        int c = t & 31, k = t >> 5;
        float s = 0.f;
        #pragma unroll
        for (int i = 0; i < 8; ++i) s += statsIn[(size_t)(k * 8 + i) * 32 + c];
        sred[k][c] = s;
    }
    for (int i = t; i < NCLS * 16; i += 256) w[i] = w3[i];
    if (t < NCLS) bb[t] = b3[t];
    __syncthreads();
    if (t < 32) {
        float a = 0.f;
        #pragma unroll
        for (int i = 0; i < 8; ++i) a += sred[i][t];
        sred[0][t] = a;
    }
    __syncthreads();
    if (t < 16) {
        const float N = (float)(NB * PL);
        float mean = sred[0][t] / N;
        float var  = sred[0][16 + t] / N - mean * mean;
        float scale = gIn[t] * rsqrtf(var + EPSF);
        sc[t] = scale;
        sh[t] = bbIn[t] - mean * scale;
    }
    __syncthreads();
    if (t < 48) {
        int cse = t >> 4, ci = t & 15;
        sG2[cse][ci] = gelu_exact(fmaf(bf2f((short)v2c[cse * 16 + ci]), sc[ci], sh[ci]));
    }
    __syncthreads();
    if (t < 3 * NCLS) {
        int cse = t / NCLS, cls = t % NCLS;
        float a = bb[cls];
        #pragma unroll
        for (int ci = 0; ci < 16; ++ci) a = fmaf(sG2[cse][ci], w[cls * 16 + ci], a);
        sV3[cse][cls] = a;
    }
    __syncthreads();

    #pragma unroll
    for (int half = 0; half < 2; ++half) {
        size_t i = (size_t)blockIdx.x * 512 + half * 256 + t;
        size_t b = i / PL, sp = i % PL;
        int x = (int)(sp / (GY * GZ));
        int yz = (int)(sp % (GY * GZ));
        int y = yz / GZ, z = yz & 15;
        float* op = out + b * NCLS * PL + sp;

        bool skip = (F2[b * 1250 + (x >> 2) * 25 + (y >> 3)] != 0);
        if (skip) {
            int cse = (z == 0) ? 0 : ((z == 15) ? 2 : 1);
            #pragma unroll
            for (int cls = 0; cls < NCLS; ++cls) op[(size_t)cls * PL] = sV3[cse][cls];
        } else {
            const short8* p = (const short8*)(act + i * 16);
            short8 v0 = p[0], v1 = p[1];
            float vi[16];
            #pragma unroll
            for (int e = 0; e < 8; ++e) {
                vi[e]     = gelu_exact(fmaf(bf2f(v0[e]), sc[e],     sh[e]));
                vi[8 + e] = gelu_exact(fmaf(bf2f(v1[e]), sc[8 + e], sh[8 + e]));
            }
            #pragma unroll
            for (int cls = 0; cls < NCLS; ++cls) {
                float a = bb[cls];
                #pragma unroll
                for (int ci = 0; ci < 16; ++ci) a = fmaf(vi[ci], w[cls * 16 + ci], a);
                op[(size_t)cls * PL] = a;
            }
        }
    }
}

// ---------------- launch ----------------
extern "C" void kernel_launch(void* const* d_in, const int* in_sizes, int n_in,
                              void* d_out, int out_size, void* d_ws, size_t ws_size,
                              hipStream_t stream)
{
    const float* tokens = (const float*)d_in[0];
    const float* depth  = (const float*)d_in[1];
    const float* intr   = (const float*)d_in[2];
    const float* c2w    = (const float*)d_in[3];
    const float* l2w    = (const float*)d_in[4];
    const float* ln_g   = (const float*)d_in[5];
    const float* ln_b   = (const float*)d_in[6];
    const float* w1     = (const float*)d_in[7];
    const float* b1     = (const float*)d_in[8];
    const float* w2     = (const float*)d_in[9];
    const float* b2     = (const float*)d_in[10];
    const float* cv1w   = (const float*)d_in[11];
    const float* cv1b   = (const float*)d_in[12];
    const float* bn1g   = (const float*)d_in[13];
    const float* bn1b   = (const float*)d_in[14];
    const float* cv2w   = (const float*)d_in[15];
    const float* cv2b   = (const float*)d_in[16];
    const float* bn2g   = (const float*)d_in[17];
    const float* bn2b   = (const float*)d_in[18];
    const float* cv3w   = (const float*)d_in[19];
    const float* cv3b   = (const float*)d_in[20];

    if (ws_size < WS_FLOATS * sizeof(float)) return;

    float* ws   = (float*)d_ws;
    float* volf = ws + OFF_VOL;
    float* cntp = ws + OFF_CNT;
    float* st1  = ws + OFF_ST1;
    float* st2s = ws + OFF_ST2;
    float* mats = ws + OFF_MATS;
    __hip_bfloat16* wGm  = (__hip_bfloat16*)(ws + OFF_WGM);
    __hip_bfloat16* wA2  = (__hip_bfloat16*)(ws + OFF_WA2);
    float* c12  = ws + OFF_C12;
    __hip_bfloat16* wB1a = (__hip_bfloat16*)(ws + OFF_WB1A);
    __hip_bfloat16* wB1m = (__hip_bfloat16*)(ws + OFF_WB1M);
    __hip_bfloat16* wB2  = (__hip_bfloat16*)(ws + OFF_WB2);
    float* S3p  = ws + OFF_S3;
    unsigned char*  F1p = (unsigned char*)(ws + OFF_F1);
    unsigned char*  F2p = (unsigned char*)(ws + OFF_F2);
    unsigned short* v2c = (unsigned short*)(ws + OFF_V2C);

    __hip_bfloat16* ob      = (__hip_bfloat16*)d_out;
    __hip_bfloat16* staged2 = ob + DO_ST2;      // padded conv1 out (raw, pre-BN)
    float* dmean            = (float*)(ob + DO_DM);
    __hip_bfloat16* staged3 = (__hip_bfloat16*)(ws + OFF_VOL);  // unpadded conv2 out
    float* outp = (float*)d_out;

    occ_prep0_kernel<<<1, 256, 0, stream>>>(intr, c2w, l2w, w1, ln_g, ln_b, b1, cv2w,
                                            mats, c12, S3p);

    occ_front_kernel<<<NT / 4, 256, 0, stream>>>(
        depth, mats, w1, ln_g, w2, cv1w, cv2w,
        wGm, wA2, wB1a, wB1m, wB2,
        dmean, volf, (float4*)(ws + OFF_CNT));

    const int TGBLK = (NT / 16 + 1 + 3) / 4;   // 257 blocks x 4 groups x (2 K-halves)
    occ_tokgemm_kernel<<<TGBLK, 512, 0, stream>>>(
        tokens, dmean, wGm, wA2, c12, b2, mats, volf, cntp);

    const int CGRID = NB * (GX / 4) * (GY / 8);   // 2500
    occ_conv_kernel<0><<<CGRID, 256, 0, stream>>>(volf, cntp, nullptr,
                                                  nullptr, nullptr, nullptr, nullptr,
                                                  nullptr, F1p, F2p, v2c,
                                                  wB1a, wB1m, cv1b, staged2, st1);
    occ_conv_kernel<1><<<CGRID, 256, 0, stream>>>(nullptr, nullptr, staged2,
                                                  st1, bn1g, bn1b, cv1b,
                                                  S3p, F1p, F2p, v2c,
                                                  wB2, nullptr, cv2b, staged3, st2s);
    occ_conv3_kernel<<<2500, 256, 0, stream>>>(staged3, st2s, bn2g, bn2b, F2p, v2c,
                                               cv3w, cv3b, outp);
}

// Round 16
// 100.356 us; speedup vs baseline: 1.0832x; 1.0832x over previous
//
#include <hip/hip_runtime.h>
#include <hip/hip_bf16.h>
#include <math.h>

// ---------------- problem constants ----------------
#define PATCH 14
#define HID   16
#define NCLS  20
#define GX    200
#define GY    200
#define GZ    16
#define NB    2
#define NCAM  6
#define PH    37
#define PW    37
#define NP    (PH*PW)
#define NT    (NB*NCAM*NP)         // 16428 tokens
#define TD    768
#define IMH   518
#define IMW   518
#define PL    ((size_t)GX*GY*GZ)   // 640000 voxels per batch
#define EPSF  1e-5f

// padded conv layout: [b][px 0..201][py 0..201][pz 0..17] rows of 16 ch
#define PX 202
#define PY 202
#define PZ 18

// ---------------- workspace layout (float units) ----------------
#define OFF_VOL   ((size_t)0)            // volf [b][sp][16] fp32 (aliased as staged3 bf16)
#define OFF_CNT   ((size_t)20480000)
#define OFF_ST1   ((size_t)21760000)
#define OFF_ST2   ((size_t)21762048)
#define ZERO_F    ((size_t)21764096)     // zeroing covers OFF_CNT..ZERO_F (done in front kernel)
#define OFF_MATS  ((size_t)21764096)     // 144
#define OFF_WGM   ((size_t)21764240)     // 24*64*8 bf16 = 6,144 f
#define OFF_WA2   ((size_t)21770384)     // 64*8 bf16 = 256 f
#define OFF_C12   ((size_t)21770640)     // 32
#define OFF_WB1A  ((size_t)21770672)     // 3,584
#define OFF_WB1M  ((size_t)21774256)     // 256
#define OFF_WB2   ((size_t)21774512)     // 3,584
#define OFF_S3    ((size_t)21778096)     // 3*16*16 fp32 tap-sums = 768
#define OFF_F1    ((size_t)21778864)     // 2500 bytes = 625 f
#define OFF_F2    ((size_t)21779489)     // 2500 bytes
#define OFF_V2C   ((size_t)21780116)     // 48 bf16 = 24 f
#define WS_FLOATS ((size_t)21780160)

#define ZERO_N4   ((int)((ZERO_F - OFF_CNT) / 4))   // 321,024 float4s

// ---------------- d_out staging (bf16 units; dead before conv3 writes) ----------
#define DO_ST2  ((size_t)0)                       // padded conv1 out, 23,503,104
#define DO_DM   ((size_t)23503104)                // dmean fp32[NT]

typedef __attribute__((ext_vector_type(8))) short short8;
typedef __attribute__((ext_vector_type(4))) float floatx4;

// fast exact-accuracy gelu: A&S 7.1.26 erf, |err| < 1.5e-7, branchless
__device__ __forceinline__ float gelu_exact(float x) {
    float ax = fabsf(x);
    float t  = ax * 0.70710678118654752f;
    float k  = 1.0f / fmaf(t, 0.3275911f, 1.0f);
    float p  = fmaf(k, 1.061405429f, -1.453152027f);
    p = fmaf(p, k, 1.421413741f);
    p = fmaf(p, k, -0.284496736f);
    p = fmaf(p, k, 0.254829592f);
    p = p * k;
    float e = __expf(-t * t);
    float erfabs = fmaf(-p, e, 1.0f);
    return fmaf(0.5f * ax, erfabs, 0.5f * x);
}
__device__ __forceinline__ unsigned short f2bf(float f) {
    __hip_bfloat16 h = __float2bfloat16(f);
    return __builtin_bit_cast(unsigned short, h);
}
__device__ __forceinline__ float bf2f(short u) {
    unsigned int b = ((unsigned int)(unsigned short)u) << 16;
    return __builtin_bit_cast(float, b);
}
__device__ __forceinline__ short8 zero8() {
    short8 z = {0,0,0,0,0,0,0,0};
    return z;
}

// shared geometry: token -> voxel (must match EXACTLY between zero-pass and tokgemm)
__device__ __forceinline__ bool tok_voxel(int tk, float dmr, const float* __restrict__ mats,
                                          int& b, size_t& sp)
{
    int bc = tk / NP;
    int p  = tk - bc * NP;
    b = bc / NCAM;
    int gy = p / PW, gx = p - gy * PW;
    const float* M = mats + bc * 12;
    float dm = fmaxf(dmr, 0.f);
    float u = (gx + 0.5f) * (float)PATCH;
    float v = (gy + 0.5f) * (float)PATCH;
    float lx = (M[0] * u + M[1] * v + M[2]) * dm + M[9];
    float ly = (M[3] * u + M[4] * v + M[5]) * dm + M[10];
    float lz = (M[6] * u + M[7] * v + M[8]) * dm + M[11];
    int cx = (int)floorf((lx + 40.0f) / 0.4f);
    int cy = (int)floorf((ly + 40.0f) / 0.4f);
    int cz = (int)floorf((lz + 1.0f) / 0.4f);
    bool valid = (dmr > 0.001f) &&
                 (unsigned)cx < (unsigned)GX &&
                 (unsigned)cy < (unsigned)GY &&
                 (unsigned)cz < (unsigned)GZ;
    sp = ((size_t)cx * GY + cy) * GZ + cz;
    return valid;
}

// ---------------- 3x3 / 4x4 inverse in double ----------------
__device__ void inv3d(const double* m, double* o) {
    double a=m[0],b=m[1],c=m[2],d=m[3],e=m[4],f=m[5],g=m[6],h=m[7],i=m[8];
    double A=e*i-f*h, B=-(d*i-f*g), C=d*h-e*g;
    double det=a*A+b*B+c*C, id=1.0/det;
    o[0]=A*id;            o[1]=-(b*i-c*h)*id;   o[2]=(b*f-c*e)*id;
    o[3]=B*id;            o[4]=(a*i-c*g)*id;    o[5]=-(a*f-c*d)*id;
    o[6]=C*id;            o[7]=-(a*h-b*g)*id;   o[8]=(a*e-b*d)*id;
}

__device__ void inv4d(const double* m, double* o) {
    double i0  =  m[5]*m[10]*m[15]-m[5]*m[11]*m[14]-m[9]*m[6]*m[15]+m[9]*m[7]*m[14]+m[13]*m[6]*m[11]-m[13]*m[7]*m[10];
    double i4  = -m[4]*m[10]*m[15]+m[4]*m[11]*m[14]+m[8]*m[6]*m[15]-m[8]*m[7]*m[14]-m[12]*m[6]*m[11]+m[12]*m[7]*m[10];
    double i8  =  m[4]*m[9]*m[15]-m[4]*m[11]*m[13]-m[8]*m[5]*m[15]+m[8]*m[7]*m[13]+m[12]*m[5]*m[11]-m[12]*m[7]*m[9];
    double i12 = -m[4]*m[9]*m[14]+m[4]*m[10]*m[13]+m[8]*m[5]*m[14]-m[8]*m[6]*m[13]-m[12]*m[5]*m[10]+m[12]*m[6]*m[9];
    double i1  = -m[1]*m[10]*m[15]+m[1]*m[11]*m[14]+m[9]*m[2]*m[15]-m[9]*m[3]*m[14]-m[13]*m[2]*m[11]+m[13]*m[3]*m[10];
    double i5  =  m[0]*m[10]*m[15]-m[0]*m[11]*m[14]-m[8]*m[2]*m[15]+m[8]*m[3]*m[14]+m[12]*m[2]*m[11]-m[12]*m[3]*m[10];
    double i9  = -m[0]*m[9]*m[15]+m[0]*m[11]*m[13]+m[8]*m[1]*m[15]-m[8]*m[3]*m[13]-m[12]*m[1]*m[11]+m[12]*m[3]*m[9];
    double i13 =  m[0]*m[9]*m[14]-m[0]*m[10]*m[13]-m[8]*m[1]*m[14]+m[8]*m[2]*m[13]+m[12]*m[1]*m[10]-m[12]*m[2]*m[9];
    double i2  =  m[1]*m[6]*m[15]-m[1]*m[7]*m[14]-m[5]*m[2]*m[15]+m[5]*m[3]*m[14]+m[13]*m[2]*m[7]-m[13]*m[3]*m[6];
    double i6  = -m[0]*m[6]*m[15]+m[0]*m[7]*m[14]+m[4]*m[2]*m[15]-m[4]*m[3]*m[14]-m[12]*m[2]*m[7]+m[12]*m[3]*m[6];
    double i10 =  m[0]*m[5]*m[15]-m[0]*m[7]*m[13]-m[4]*m[1]*m[15]+m[4]*m[3]*m[13]+m[12]*m[1]*m[7]-m[12]*m[3]*m[5];
    double i14 = -m[0]*m[5]*m[14]+m[0]*m[6]*m[13]+m[4]*m[1]*m[14]-m[4]*m[2]*m[13]-m[12]*m[1]*m[6]+m[12]*m[2]*m[5];
    double i3  = -m[1]*m[6]*m[11]+m[1]*m[7]*m[10]+m[5]*m[2]*m[11]-m[5]*m[3]*m[10]-m[9]*m[2]*m[7]+m[9]*m[3]*m[6];
    double i7  =  m[0]*m[6]*m[11]-m[0]*m[7]*m[10]-m[4]*m[2]*m[11]+m[4]*m[3]*m[10]+m[8]*m[2]*m[7]-m[8]*m[3]*m[6];
    double i11 = -m[0]*m[5]*m[11]+m[0]*m[7]*m[9]+m[4]*m[1]*m[11]-m[4]*m[3]*m[9]-m[8]*m[1]*m[7]+m[8]*m[3]*m[5];
    double i15 =  m[0]*m[5]*m[10]-m[0]*m[6]*m[9]-m[4]*m[1]*m[10]+m[4]*m[2]*m[9]+m[8]*m[1]*m[6]-m[8]*m[2]*m[5];
    double det = m[0]*i0+m[1]*i4+m[2]*i8+m[3]*i12;
    double id = 1.0/det;
    o[0]=i0*id; o[1]=i1*id; o[2]=i2*id; o[3]=i3*id;
    o[4]=i4*id; o[5]=i5*id; o[6]=i6*id; o[7]=i7*id;
    o[8]=i8*id; o[9]=i9*id; o[10]=i10*id; o[11]=i11*id;
    o[12]=i12*id; o[13]=i13*id; o[14]=i14*id; o[15]=i15*id;
}

// compute cam bc's fused matrix (rows of 12 floats) -- deterministic everywhere
__device__ void cam_mat(int t, const float* __restrict__ intr, const float* __restrict__ c2w,
                        const float* __restrict__ l2w, float* __restrict__ out12)
{
    int b = t / NCAM;
    double K[9], Ki[9], L[16], Li[16], C[16], M[16], A[9];
    #pragma unroll
    for (int i = 0; i < 9; ++i) K[i] = (double)intr[t * 9 + i];
    inv3d(K, Ki);
    #pragma unroll
    for (int i = 0; i < 16; ++i) L[i] = (double)l2w[b * 16 + i];
    inv4d(L, Li);
    #pragma unroll
    for (int i = 0; i < 16; ++i) C[i] = (double)c2w[t * 16 + i];
    #pragma unroll
    for (int r = 0; r < 4; ++r)
        #pragma unroll
        for (int c = 0; c < 4; ++c) {
            double s = 0.0;
            #pragma unroll
            for (int k = 0; k < 4; ++k) s += Li[r * 4 + k] * C[k * 4 + c];
            M[r * 4 + c] = s;
        }
    #pragma unroll
    for (int r = 0; r < 3; ++r)
        #pragma unroll
        for (int c = 0; c < 3; ++c) {
            double s = 0.0;
            #pragma unroll
            for (int k = 0; k < 3; ++k) s += M[r * 4 + k] * Ki[k * 3 + c];
            A[r * 3 + c] = s;
        }
    #pragma unroll
    for (int i = 0; i < 9; ++i) out12[i] = (float)A[i];
    out12[9]  = (float)M[3];
    out12[10] = (float)M[7];
    out12[11] = (float)M[11];
}

// ---- front kernel: depth means + vol scatter-zero + cnt/stats zero + weight prep ----
__global__ __launch_bounds__(256) void occ_front_kernel(
    const float* __restrict__ depth, const float* __restrict__ intr,
    const float* __restrict__ c2w, const float* __restrict__ l2w,
    const float* __restrict__ w1, const float* __restrict__ ln_g,
    const float* __restrict__ ln_b, const float* __restrict__ b1,
    const float* __restrict__ w2, const float* __restrict__ cw1,
    const float* __restrict__ cw2,
    float* __restrict__ mats, __hip_bfloat16* __restrict__ wGm,
    __hip_bfloat16* __restrict__ wA2, float* __restrict__ c12,
    __hip_bfloat16* __restrict__ wB1a, __hip_bfloat16* __restrict__ wB1m,
    __hip_bfloat16* __restrict__ wB2, float* __restrict__ S3,
    float* __restrict__ dmean, float* __restrict__ vol, float4* __restrict__ zbase)
{
    __shared__ float smats[NB * NCAM * 12];
    int tid = threadIdx.x;
    int bid = blockIdx.x;
    int gt = bid * 256 + tid;

    if (gt < ZERO_N4) {
        float4 z = {0.f, 0.f, 0.f, 0.f};
        zbase[gt] = z;
    }

    int l = tid & 63;
    int g = bid * 4 + (tid >> 6);
    int bc = g / NP;
    int p  = g - bc * NP;
    int gy = p / PW, gx = p - gy * PW;
    const float* dbase = depth + (size_t)bc * (IMH * IMW);
    int rbase = gy * PATCH, cb = gx * PATCH;
    float dsum = 0.f;
    #pragma unroll
    for (int i = 0; i < 3; ++i) {
        int idx = l + 64 * i;
        int py = idx / 14;
        int px = idx - py * 14;
        dsum += dbase[(size_t)(rbase + py) * IMW + (cb + px)];
    }
    if (l < 4)
        dsum += dbase[(size_t)(rbase + 13) * IMW + (cb + 10 + l)];

    if (tid < NB * NCAM) {
        cam_mat(tid, intr, c2w, l2w, &smats[tid * 12]);
        if (bid == 0) {
            #pragma unroll
            for (int i = 0; i < 12; ++i) mats[tid * 12 + i] = smats[tid * 12 + i];
        }
    }

    if (gt < 24 * 64 * 8) {
        int i = gt;
        int st = i >> 9; int ln = (i >> 3) & 63; int e = i & 7;
        int kg = ln >> 4, j = ln & 15;
        int d = st * 32 + kg * 8 + e;
        wGm[i] = __float2bfloat16(ln_g[d] * w1[d * 16 + j]);
    }
    if (gt < 64 * 8) {
        int i = gt;
        int ln = i >> 3; int e = i & 7;
        int kg = ln >> 4, ch = ln & 15;
        int k = kg * 8 + e;
        wA2[i] = __float2bfloat16((k < 16) ? w2[k * 16 + ch] : 0.f);
    }
    if (gt < 14 * 64 * 8) {
        int i = gt;
        int t2 = i >> 9; int r = i & 511; int ln = r >> 3; int e = r & 7;
        int kg = ln >> 4;
        int tt = 2 * t2 + (kg >> 1);
        int ci = ((kg & 1) << 3) + e;
        int o = ln & 15;
        float val = (tt < 27) ? cw1[(o * 17 + ci) * 27 + tt] : 0.f;
        wB1a[i] = __float2bfloat16(val);
    }
    if (gt < 64 * 8) {
        int i = gt;
        int ln = i >> 3; int e = i & 7;
        int k = ((ln >> 4) << 3) + e;
        int o = ln & 15;
        float val = (k < 27) ? cw1[(o * 17 + 16) * 27 + k] : 0.f;
        wB1m[i] = __float2bfloat16(val);
    }
    if (gt < 14 * 64 * 8) {
        int i = gt;
        int t2 = i >> 9; int r = i & 511; int ln = r >> 3; int e = r & 7;
        int kg = ln >> 4;
        int tt = 2 * t2 + (kg >> 1);
        int ci = ((kg & 1) << 3) + e;
        int o = ln & 15;
        float val = (tt < 27) ? cw2[(o * 16 + ci) * 27 + tt] : 0.f;
        wB2[i] = __float2bfloat16(val);
    }
    // conv2 tap-sums for const-tile path: S3[case][o][ci]
    if (gt < 3 * 16 * 16) {
        int cse = gt >> 8; int r = gt & 255; int o = r >> 4; int ci = r & 15;
        int kwlo = (cse == 0) ? 1 : 0;
        int kwhi = (cse == 2) ? 1 : 2;
        float s = 0.f;
        for (int kd = 0; kd < 3; ++kd)
            for (int kh = 0; kh < 3; ++kh)
                for (int kw = kwlo; kw <= kwhi; ++kw)
                    s += bf2f((short)f2bf(cw2[(o * 16 + ci) * 27 + (kd * 9 + kh * 3 + kw)]));
        S3[gt] = s;
    }

    if (bid == 0) {
        __shared__ float sc1[256], sc2[256];
        int j = tid & 15, ck = tid >> 4;
        float c1 = 0.f, c2p = 0.f;
        #pragma unroll 4
        for (int dd = 0; dd < TD / 16; ++dd) {
            int d = ck * (TD / 16) + dd;
            c1  += bf2f((short)f2bf(ln_g[d] * w1[d * 16 + j]));
            c2p += ln_b[d] * w1[d * 16 + j];
        }
        sc1[tid] = c1; sc2[tid] = c2p;
        __syncthreads();
        if (tid < 16) {
            float a1 = 0.f, a2 = 0.f;
            #pragma unroll
            for (int k = 0; k < 16; ++k) { a1 += sc1[k * 16 + tid]; a2 += sc2[k * 16 + tid]; }
            c12[tid] = a1;
            c12[16 + tid] = a2 + b1[tid];
        }
    }

    __syncthreads();

    #pragma unroll
    for (int m = 1; m <= 32; m <<= 1) dsum += __shfl_xor(dsum, m);
    float dmr = dsum * (1.0f / 196.0f);
    if (l == 0) dmean[g] = dmr;
    if (l < 4) {
        int b; size_t sp;
        if (tok_voxel(g, dmr, smats, b, sp)) {
            float4 z = {0.f, 0.f, 0.f, 0.f};
            *(float4*)(vol + ((size_t)b * PL + sp) * 16 + l * 4) = z;
        }
    }
}

// ------- token GEMM: K-split x2 (2 waves per 16-token group); LN in epilogue -------
__global__ __launch_bounds__(512) void occ_tokgemm_kernel(
    const float* __restrict__ tokens, const float* __restrict__ dmean,
    const __hip_bfloat16* __restrict__ wGm, const __hip_bfloat16* __restrict__ wA2,
    const float* __restrict__ c12, const float* __restrict__ b2,
    const float* __restrict__ mats, float* __restrict__ vol, float* __restrict__ cnt)
{
    int tid = threadIdx.x;
    int w = tid >> 6, lane = tid & 63;
    int grp = w & 3, half = w >> 2;
    int tile = (blockIdx.x * 4 + grp) * 16;
    int j16 = lane & 15, kg = lane >> 4;

    __shared__ float sPart[4][64][6];          // partials from half=1 waves
    __shared__ __hip_bfloat16 sH[4][16][16];

    int tka  = tile + j16;
    int tkac = min(tka, NT - 1);

    const float* tokp = tokens + (size_t)tkac * TD + (kg << 3);
    const short8* wg8 = (const short8*)wGm;

    floatx4 acc = {0.f, 0.f, 0.f, 0.f};
    float s = 0.f, sq = 0.f;
    #pragma unroll
    for (int st2 = 0; st2 < 12; ++st2) {
        int st = half * 12 + st2;
        float4 xa = *(const float4*)(tokp + st * 32);
        float4 xb = *(const float4*)(tokp + st * 32 + 4);
        s += xa.x + xa.y + xa.z + xa.w + xb.x + xb.y + xb.z + xb.w;
        sq = fmaf(xa.x, xa.x, sq); sq = fmaf(xa.y, xa.y, sq);
        sq = fmaf(xa.z, xa.z, sq); sq = fmaf(xa.w, xa.w, sq);
        sq = fmaf(xb.x, xb.x, sq); sq = fmaf(xb.y, xb.y, sq);
        sq = fmaf(xb.z, xb.z, sq); sq = fmaf(xb.w, xb.w, sq);
        short8 a;
        a[0] = (short)f2bf(xa.x); a[1] = (short)f2bf(xa.y);
        a[2] = (short)f2bf(xa.z); a[3] = (short)f2bf(xa.w);
        a[4] = (short)f2bf(xb.x); a[5] = (short)f2bf(xb.y);
        a[6] = (short)f2bf(xb.z); a[7] = (short)f2bf(xb.w);
        acc = __builtin_amdgcn_mfma_f32_16x16x32_bf16(a, wg8[st * 64 + lane], acc, 0, 0, 0);
    }

    if (half == 1) {
        sPart[grp][lane][0] = acc[0]; sPart[grp][lane][1] = acc[1];
        sPart[grp][lane][2] = acc[2]; sPart[grp][lane][3] = acc[3];
        sPart[grp][lane][4] = s;      sPart[grp][lane][5] = sq;
    }
    __syncthreads();

    if (half == 0) {
        acc[0] += sPart[grp][lane][0]; acc[1] += sPart[grp][lane][1];
        acc[2] += sPart[grp][lane][2]; acc[3] += sPart[grp][lane][3];
        s += sPart[grp][lane][4];      sq += sPart[grp][lane][5];

        s  += __shfl_xor(s, 16);  s  += __shfl_xor(s, 32);
        sq += __shfl_xor(sq, 16); sq += __shfl_xor(sq, 32);
        float mu = s * (1.0f / (float)TD);
        float rs = rsqrtf(sq * (1.0f / (float)TD) - mu * mu + EPSF);

        float c1  = c12[j16];
        float c2p = c12[16 + j16];
        #pragma unroll
        for (int r = 0; r < 4; ++r) {
            int srcl = kg * 4 + r;
            float mur = __shfl(mu, srcl, 16);
            float rsr = __shfl(rs, srcl, 16);
            float h = rsr * (acc[r] - mur * c1) + c2p;
            sH[grp][srcl][j16] = __float2bfloat16(gelu_exact(h));
        }
    }
    __syncthreads();

    if (half == 0) {
        short8 hb = zero8();
        if (kg < 2) hb = *(const short8*)&sH[grp][j16][kg * 8];
        floatx4 acc2;
        acc2[0] = b2[kg * 4 + 0]; acc2[1] = b2[kg * 4 + 1];
        acc2[2] = b2[kg * 4 + 2]; acc2[3] = b2[kg * 4 + 3];
        short8 a2 = ((const short8*)wA2)[lane];
        acc2 = __builtin_amdgcn_mfma_f32_16x16x32_bf16(a2, hb, acc2, 0, 0, 0);

        int b; size_t sp;
        bool valid = tok_voxel(tkac, dmean[tkac], mats, b, sp) && (tka < NT);
        if (valid) {
            float* base = vol + ((size_t)b * PL + sp) * 16 + kg * 4;
            atomicAdd(base + 0, acc2[0]);
            atomicAdd(base + 1, acc2[1]);
            atomicAdd(base + 2, acc2[2]);
            atomicAdd(base + 3, acc2[3]);
            if (kg == 0) atomicAdd(cnt + (size_t)b * PL + sp, 1.0f);
        }
    }
}

// ------- conv3d 3x3x3 via MFMA, LDS-staged 4x8 tile, sparse tile+write skipping -------
// MODE 0 (conv1): normalize-on-stage; empty -> flag F1, skip MFMA AND stores
// MODE 1 (conv2): bn1-finalize; stage substitutes const for F1 rows; const tile ->
//                 skip stage/MFMA/stores (conv3 uses sV3 via F2)
template <int MODE>
__global__ __launch_bounds__(256, 4) void occ_conv_kernel(
    const float* __restrict__ volf, const float* __restrict__ cnt,
    const __hip_bfloat16* __restrict__ inbf,
    const float* __restrict__ statsIn, const float* __restrict__ gIn,
    const float* __restrict__ bbIn, const float* __restrict__ cv1bIn,
    const float* __restrict__ S3, unsigned char* __restrict__ F1,
    unsigned char* __restrict__ F2, unsigned short* __restrict__ v2c,
    const __hip_bfloat16* __restrict__ wBa, const __hip_bfloat16* __restrict__ wBm,
    const float* __restrict__ bias, __hip_bfloat16* __restrict__ out,
    float* __restrict__ statsOut)
{
    int bid = blockIdx.x;
    int xcd = bid & 7, off = bid >> 3;
    int blk = (xcd < 4 ? xcd * 313 : 4 * 313 + (xcd - 4) * 312) + off;
    int b   = blk / 1250;
    int rem = blk % 1250;
    int x0  = (rem / 25) * 4;
    int y0  = (rem % 25) * 8;
    int tid = threadIdx.x;

    __shared__ __hip_bfloat16 sA[1080 * 16];
    __shared__ unsigned short sM[1080];
    __shared__ float sred[8][32];
    __shared__ float sbn[32];
    __shared__ float sG1[16];
    __shared__ unsigned short sGBc[16];   // bf16 of gelu(bn1(bf16(cv1b)))
    __shared__ float sV[3][16];
    __shared__ int sFlag;

    if constexpr (MODE == 1) {
        {
            int c = tid & 31, k = tid >> 5;
            float s = 0.f;
            #pragma unroll
            for (int i = 0; i < 8; ++i) s += statsIn[(size_t)(k * 8 + i) * 32 + c];
            sred[k][c] = s;
        }
        __syncthreads();
        if (tid < 32) {
            float a = 0.f;
            #pragma unroll
            for (int i = 0; i < 8; ++i) a += sred[i][tid];
            sred[0][tid] = a;
        }
        __syncthreads();
        if (tid < 16) {
            const float N = (float)(NB * PL);
            float mean = sred[0][tid] / N;
            float var  = sred[0][16 + tid] / N - mean * mean;
            float scale = gIn[tid] * rsqrtf(var + EPSF);
            sbn[tid] = scale;
            sbn[16 + tid] = bbIn[tid] - mean * scale;
        }
        if (tid == 0) {
            int xt = rem / 25, yt = rem % 25;
            int ok = (xt >= 1 && xt <= 48 && yt >= 1 && yt <= 23) ? 1 : 0;
            if (ok) {
                #pragma unroll
                for (int dx = -1; dx <= 1; ++dx)
                    #pragma unroll
                    for (int dy = -1; dy <= 1; ++dy)
                        if (!F1[b * 1250 + (xt + dx) * 25 + (yt + dy)]) ok = 0;
            }
            sFlag = ok;
        }
        __syncthreads();
        if (tid < 16) {
            float bf16bias = bf2f((short)f2bf(cv1bIn[tid]));
            float gval = gelu_exact(fmaf(bf16bias, sbn[tid], sbn[16 + tid]));
            sG1[tid] = gval;
            sGBc[tid] = f2bf(gval);
        }
        __syncthreads();
    } else {
        if (tid == 0) sFlag = 0;
        __syncthreads();
    }

    bool skip2 = false;
    if constexpr (MODE == 1) skip2 = (sFlag != 0);

    if (!skip2) {
        short8* sa8 = (short8*)sA;
        const short8* gin = (const short8*)inbf;
        for (int ii = tid; ii < 1080; ii += 256) {
            int dx = ii / 180;
            int r2 = ii - dx * 180;
            int dy = r2 / 18, dz = r2 - dy * 18;
            int px = x0 + dx, py = y0 + dy, pz = dz;
            bool interior = ((unsigned)(px - 1) < (unsigned)GX) &&
                            ((unsigned)(py - 1) < (unsigned)GY) &&
                            ((unsigned)(pz - 1) < (unsigned)GZ);
            short8 o0 = zero8(), o1 = zero8();
            if constexpr (MODE == 0) {
                unsigned short m = 0;
                if (interior) {
                    size_t vi = (size_t)b * PL +
                                (((size_t)(px - 1) * GY + (py - 1)) * GZ + (pz - 1));
                    float cn = cnt[vi];
                    if (cn > 0.f) {
                        float inv = 1.0f / cn;
                        const float4* vp = (const float4*)(volf + vi * 16);
                        float4 f0 = vp[0], f1 = vp[1], f2 = vp[2], f3 = vp[3];
                        o0[0] = (short)f2bf(f0.x * inv); o0[1] = (short)f2bf(f0.y * inv);
                        o0[2] = (short)f2bf(f0.z * inv); o0[3] = (short)f2bf(f0.w * inv);
                        o0[4] = (short)f2bf(f1.x * inv); o0[5] = (short)f2bf(f1.y * inv);
                        o0[6] = (short)f2bf(f1.z * inv); o0[7] = (short)f2bf(f1.w * inv);
                        o1[0] = (short)f2bf(f2.x * inv); o1[1] = (short)f2bf(f2.y * inv);
                        o1[2] = (short)f2bf(f2.z * inv); o1[3] = (short)f2bf(f2.w * inv);
                        o1[4] = (short)f2bf(f3.x * inv); o1[5] = (short)f2bf(f3.y * inv);
                        o1[6] = (short)f2bf(f3.z * inv); o1[7] = (short)f2bf(f3.w * inv);
                        m = f2bf(1.0f);
                        sFlag = 1;                       // benign race: any-occupied
                    }
                }
                sM[ii] = m;
            } else {
                if (interior) {
                    int ti = b * 1250 + ((px - 1) >> 2) * 25 + ((py - 1) >> 3);
                    if (F1[ti]) {
                        #pragma unroll
                        for (int e = 0; e < 8; ++e) {
                            o0[e] = (short)sGBc[e];
                            o1[e] = (short)sGBc[8 + e];
                        }
                    } else {
                        size_t grow = ((size_t)((b * PX + px) * PY + py) * PZ) + pz;
                        short8 v0 = gin[grow * 2], v1 = gin[grow * 2 + 1];
                        #pragma unroll
                        for (int e = 0; e < 8; ++e) {
                            o0[e] = (short)f2bf(gelu_exact(fmaf(bf2f(v0[e]), sbn[e],     sbn[16 + e])));
                            o1[e] = (short)f2bf(gelu_exact(fmaf(bf2f(v1[e]), sbn[8 + e], sbn[24 + e])));
                        }
                    }
                }
            }
            sa8[ii * 2] = o0; sa8[ii * 2 + 1] = o1;
        }
    }
    __syncthreads();

    bool empty1 = false;
    if constexpr (MODE == 0) {
        empty1 = (sFlag == 0);
        if (tid == 0) F1[b * 1250 + rem] = empty1 ? 1 : 0;
    } else {
        if (skip2 && tid < 48) {
            int cse = tid >> 4, o = tid & 15;
            float a = bias[o];
            #pragma unroll
            for (int ci = 0; ci < 16; ++ci)
                a = fmaf(sG1[ci], S3[cse * 256 + o * 16 + ci], a);
            sV[cse][o] = a;
            v2c[tid] = f2bf(a);
        }
        if (tid == 0) F2[b * 1250 + rem] = skip2 ? 1 : 0;
        __syncthreads();
    }

    int w = tid >> 6, lane = tid & 63;
    int z = lane & 15, kg = lane >> 4;
    int ci0 = (kg & 1) << 3;
    bool halfsel = kg >= 2;

    float bo = bias[lane & 15];
    floatx4 acc[8];
    #pragma unroll
    for (int j = 0; j < 8; ++j) { acc[j][0]=bo; acc[j][1]=bo; acc[j][2]=bo; acc[j][3]=bo; }

    bool doMfma = (MODE == 0) ? !empty1 : !skip2;
    if (doMfma) {
        const short8* wp = (const short8*)wBa;
        short8 wreg[14];
        #pragma unroll
        for (int t2 = 0; t2 < 14; ++t2) wreg[t2] = wp[t2 * 64 + lane];

        #pragma unroll
        for (int t2 = 0; t2 < 14; ++t2) {
            const int ta = 2 * t2;
            const int tb = (2 * t2 + 1 > 26) ? 26 : 2 * t2 + 1;
            const int kda = ta / 9, kha = (ta / 3) % 3, kwa = ta % 3;
            const int kdb = tb / 9, khb = (tb / 3) % 3, kwb = tb % 3;
            int rowA = (w + kda) * 180 + kha * 18 + (z + kwa);
            int rowB = (w + kdb) * 180 + khb * 18 + (z + kwb);
            int row = halfsel ? rowB : rowA;
            const __hip_bfloat16* ap = sA + row * 16 + ci0;
            #pragma unroll
            for (int j = 0; j < 8; ++j) {
                short8 a = *(const short8*)(ap + j * (18 * 16));
                acc[j] = __builtin_amdgcn_mfma_f32_16x16x32_bf16(a, wreg[t2], acc[j], 0, 0, 0);
            }
        }

        if constexpr (MODE == 0) {
            int base8[8];
            #pragma unroll
            for (int e = 0; e < 8; ++e) {
                int tap = kg * 8 + e;
                int kd = tap / 9;
                int rm = tap - kd * 9;
                int kh = rm / 3;
                int kw = rm - kh * 3;
                int idx = (w + kd) * 180 + kh * 18 + z + kw;
                base8[e] = (tap < 27) ? idx : 0;
            }
            short8 wm = ((const short8*)wBm)[lane];
            #pragma unroll
            for (int j = 0; j < 8; ++j) {
                short8 am;
                #pragma unroll
                for (int e = 0; e < 8; ++e) am[e] = (short)sM[base8[e] + j * 18];
                acc[j] = __builtin_amdgcn_mfma_f32_16x16x32_bf16(am, wm, acc[j], 0, 0, 0);
            }
        }
    } else if (MODE == 1 && skip2) {
        int o = lane & 15;
        #pragma unroll
        for (int r = 0; r < 4; ++r) {
            int zp = kg * 4 + r;
            int cse = (zp == 0) ? 0 : ((zp == 15) ? 2 : 1);
            float v = sV[cse][o];
            #pragma unroll
            for (int j = 0; j < 8; ++j) acc[j][r] = v;
        }
    }

    bool doStore = (MODE == 0) ? !empty1 : !skip2;
    if (doStore) {
        int o = lane & 15;
        int wx = x0 + w;
        #pragma unroll
        for (int j = 0; j < 8; ++j) {
            int wy = y0 + j;
            size_t rowbase;
            if constexpr (MODE == 0)
                rowbase = (size_t)(((b * PX + wx + 1) * PY) + (wy + 1)) * PZ + 1;
            else
                rowbase = (size_t)b * PL + ((size_t)wx * GY + wy) * GZ;
            #pragma unroll
            for (int r = 0; r < 4; ++r)
                out[(rowbase + kg * 4 + r) * 16 + o] = __float2bfloat16(acc[j][r]);
        }
    }

    float s = 0.f, sq = 0.f;
    #pragma unroll
    for (int j = 0; j < 8; ++j)
        #pragma unroll
        for (int r = 0; r < 4; ++r) { float v = acc[j][r]; s += v; sq += v * v; }
    s  += __shfl_xor(s, 16);  s  += __shfl_xor(s, 32);
    sq += __shfl_xor(sq, 16); sq += __shfl_xor(sq, 32);
    __syncthreads();
    if (lane < 16) { sred[w][lane] = s; sred[w][16 + lane] = sq; }
    __syncthreads();
    if (tid < 32) {
        float v2 = sred[0][tid] + sred[1][tid] + sred[2][tid] + sred[3][tid];
        atomicAdd(&statsOut[(size_t)(blockIdx.x & 63) * 32 + tid], v2);
    }
}

// -------- conv3 1x1x1 (16 -> 20): per-block bn2 finalize, const-tile fast path,
//          2 voxels per thread (2500 blocks) --------
__global__ __launch_bounds__(256) void occ_conv3_kernel(const __hip_bfloat16* __restrict__ act,
                                                        const float* __restrict__ statsIn,
                                                        const float* __restrict__ gIn,
                                                        const float* __restrict__ bbIn,
                                                        const unsigned char* __restrict__ F2,
                                                        const unsigned short* __restrict__ v2c,
                                                        const float* __restrict__ w3,
                                                        const float* __restrict__ b3,
                                                        float* __restrict__ out)
{
    __shared__ float w[NCLS * 16];
    __shared__ float bb[NCLS];
    __shared__ float sred[8][32];
    __shared__ float sc[16], sh[16];
    __shared__ float sG2[3][16];
    __shared__ float sV3[3][NCLS];
    int t = threadIdx.x;
    {
        int c = t & 31, k = t >> 5;
        float s = 0.f;
        #pragma unroll
        for (int i = 0; i < 8; ++i) s += statsIn[(size_t)(k * 8 + i) * 32 + c];
        sred[k][c] = s;
    }
    for (int i = t; i < NCLS * 16; i += 256) w[i] = w3[i];
    if (t < NCLS) bb[t] = b3[t];
    __syncthreads();
    if (t < 32) {
        float a = 0.f;
        #pragma unroll
        for (int i = 0; i < 8; ++i) a += sred[i][t];
        sred[0][t] = a;
    }
    __syncthreads();
    if (t < 16) {
        const float N = (float)(NB * PL);
        float mean = sred[0][t] / N;
        float var  = sred[0][16 + t] / N - mean * mean;
        float scale = gIn[t] * rsqrtf(var + EPSF);
        sc[t] = scale;
        sh[t] = bbIn[t] - mean * scale;
    }
    __syncthreads();
    if (t < 48) {
        int cse = t >> 4, ci = t & 15;
        sG2[cse][ci] = gelu_exact(fmaf(bf2f((short)v2c[cse * 16 + ci]), sc[ci], sh[ci]));
    }
    __syncthreads();
    if (t < 3 * NCLS) {
        int cse = t / NCLS, cls = t % NCLS;
        float a = bb[cls];
        #pragma unroll
        for (int ci = 0; ci < 16; ++ci) a = fmaf(sG2[cse][ci], w[cls * 16 + ci], a);
        sV3[cse][cls] = a;
    }
    __syncthreads();

    #pragma unroll
    for (int half = 0; half < 2; ++half) {
        size_t i = (size_t)blockIdx.x * 512 + half * 256 + t;
        size_t b = i / PL, sp = i % PL;
        int x = (int)(sp / (GY * GZ));
        int yz = (int)(sp % (GY * GZ));
        int y = yz / GZ, z = yz & 15;
        float* op = out + b * NCLS * PL + sp;

        bool skip = (F2[b * 1250 + (x >> 2) * 25 + (y >> 3)] != 0);
        if (skip) {
            int cse = (z == 0) ? 0 : ((z == 15) ? 2 : 1);
            #pragma unroll
            for (int cls = 0; cls < NCLS; ++cls) op[(size_t)cls * PL] = sV3[cse][cls];
        } else {
            const short8* p = (const short8*)(act + i * 16);
            short8 v0 = p[0], v1 = p[1];
            float vi[16];
            #pragma unroll
            for (int e = 0; e < 8; ++e) {
                vi[e]     = gelu_exact(fmaf(bf2f(v0[e]), sc[e],     sh[e]));
                vi[8 + e] = gelu_exact(fmaf(bf2f(v1[e]), sc[8 + e], sh[8 + e]));
            }
            #pragma unroll
            for (int cls = 0; cls < NCLS; ++cls) {
                float a = bb[cls];
                #pragma unroll
                for (int ci = 0; ci < 16; ++ci) a = fmaf(vi[ci], w[cls * 16 + ci], a);
                op[(size_t)cls * PL] = a;
            }
        }
    }
}

// ---------------- launch ----------------
extern "C" void kernel_launch(void* const* d_in, const int* in_sizes, int n_in,
                              void* d_out, int out_size, void* d_ws, size_t ws_size,
                              hipStream_t stream)
{
    const float* tokens = (const float*)d_in[0];
    const float* depth  = (const float*)d_in[1];
    const float* intr   = (const float*)d_in[2];
    const float* c2w    = (const float*)d_in[3];
    const float* l2w    = (const float*)d_in[4];
    const float* ln_g   = (const float*)d_in[5];
    const float* ln_b   = (const float*)d_in[6];
    const float* w1     = (const float*)d_in[7];
    const float* b1     = (const float*)d_in[8];
    const float* w2     = (const float*)d_in[9];
    const float* b2     = (const float*)d_in[10];
    const float* cv1w   = (const float*)d_in[11];
    const float* cv1b   = (const float*)d_in[12];
    const float* bn1g   = (const float*)d_in[13];
    const float* bn1b   = (const float*)d_in[14];
    const float* cv2w   = (const float*)d_in[15];
    const float* cv2b   = (const float*)d_in[16];
    const float* bn2g   = (const float*)d_in[17];
    const float* bn2b   = (const float*)d_in[18];
    const float* cv3w   = (const float*)d_in[19];
    const float* cv3b   = (const float*)d_in[20];

    if (ws_size < WS_FLOATS * sizeof(float)) return;

    float* ws   = (float*)d_ws;
    float* volf = ws + OFF_VOL;
    float* cntp = ws + OFF_CNT;
    float* st1  = ws + OFF_ST1;
    float* st2s = ws + OFF_ST2;
    float* mats = ws + OFF_MATS;
    __hip_bfloat16* wGm  = (__hip_bfloat16*)(ws + OFF_WGM);
    __hip_bfloat16* wA2  = (__hip_bfloat16*)(ws + OFF_WA2);
    float* c12  = ws + OFF_C12;
    __hip_bfloat16* wB1a = (__hip_bfloat16*)(ws + OFF_WB1A);
    __hip_bfloat16* wB1m = (__hip_bfloat16*)(ws + OFF_WB1M);
    __hip_bfloat16* wB2  = (__hip_bfloat16*)(ws + OFF_WB2);
    float* S3p  = ws + OFF_S3;
    unsigned char*  F1p = (unsigned char*)(ws + OFF_F1);
    unsigned char*  F2p = (unsigned char*)(ws + OFF_F2);
    unsigned short* v2c = (unsigned short*)(ws + OFF_V2C);

    __hip_bfloat16* ob      = (__hip_bfloat16*)d_out;
    __hip_bfloat16* staged2 = ob + DO_ST2;      // padded conv1 out (raw, pre-BN)
    float* dmean            = (float*)(ob + DO_DM);
    __hip_bfloat16* staged3 = (__hip_bfloat16*)(ws + OFF_VOL);  // unpadded conv2 out
    float* outp = (float*)d_out;

    occ_front_kernel<<<NT / 4, 256, 0, stream>>>(
        depth, intr, c2w, l2w, w1, ln_g, ln_b, b1, w2, cv1w, cv2w,
        mats, wGm, wA2, c12, wB1a, wB1m, wB2, S3p,
        dmean, volf, (float4*)(ws + OFF_CNT));

    const int TGBLK = (NT / 16 + 1 + 3) / 4;   // 257 blocks x 4 groups x (2 K-halves)
    occ_tokgemm_kernel<<<TGBLK, 512, 0, stream>>>(
        tokens, dmean, wGm, wA2, c12, b2, mats, volf, cntp);

    const int CGRID = NB * (GX / 4) * (GY / 8);   // 2500
    occ_conv_kernel<0><<<CGRID, 256, 0, stream>>>(volf, cntp, nullptr,
                                                  nullptr, nullptr, nullptr, nullptr,
                                                  nullptr, F1p, F2p, v2c,
                                                  wB1a, wB1m, cv1b, staged2, st1);
    occ_conv_kernel<1><<<CGRID, 256, 0, stream>>>(nullptr, nullptr, staged2,
                                                  st1, bn1g, bn1b, cv1b,
                                                  S3p, F1p, F2p, v2c,
                                                  wB2, nullptr, cv2b, staged3, st2s);
    occ_conv3_kernel<<<2500, 256, 0, stream>>>(staged3, st2s, bn2g, bn2b, F2p, v2c,
                                               cv3w, cv3b, outp);
}